// Round 6
// baseline (973.097 us; speedup 1.0000x reference)
//
#include <hip/hip_runtime.h>

// ---------------------------------------------------------------------------
// TPUGEMMLinear: blockwise-fp8 quantize (block=128) of x[M,K] (along K) and
// w[K,N] (along N), dequant-scaled fp32 GEMM + bias.
// R6: de-lockstep the GEMM. R3-R5 measured cycles/iter == MFMA + LDS-read
// SUM (zero pipe overlap): the 16-barriers/iter phase structure herds all
// waves into all-read-then-all-MFMA lockstep. New structure: BK=32 K-steps,
// TRIPLE-buffered LDS (3 x 32 KB = 96 KiB), exactly 1 s_barrier + 1 counted
// WAITV(4) per step (the only syncs staging actually requires):
//   step t: WAITV(4) [confirms tile t, staged 2 steps ago ~3000 cyc cover]
//           -> s_barrier -> issue 12 ds_read_b128 (pinned) + 4 staggered
//           global_load_lds of tile t+2 into buf (t+2)%3 (= buffer freed at
//           end of step t-1) -> WAITL(6)/(2)/(0) ladder -> 4 MFMA quadrants.
// Waves drift freely within a step -> LDS reads of one wave overlap MFMA of
// another. Swizzle for 64-B rows: colslot(16B) ^= (row&3); (quad,l16) map is
// bijective per 1024-B row-block => bank-balanced, conflict-free.
// Quant kernels v3: 8 lanes per 128-block, 16 elems/lane -> 3 shfl rounds
// per 16 elems (was 5 per 4). Same op set => bit-exact with reference.
// Workspace: Xd bf16 [M*K] | Bt bf16 [N*K]  (160 MB).
// ---------------------------------------------------------------------------

typedef __attribute__((ext_vector_type(8))) short short8;   // 8 x bf16 frag
typedef __attribute__((ext_vector_type(4))) float f32x4;
typedef unsigned short ushort_t;
typedef __attribute__((address_space(3))) const char as3ch;

__device__ __forceinline__ float fp8_round_trip(float v) {
    int p = __builtin_amdgcn_cvt_pk_fp8_f32(v, v, 0, false);
    return __builtin_amdgcn_cvt_f32_fp8(p, 0);
}

__device__ __forceinline__ ushort_t f32_to_bf16(float f) {
    union { float f; unsigned u; } un; un.f = f;
    unsigned r = un.u + 0x7fffu + ((un.u >> 16) & 1u);
    return (ushort_t)(r >> 16);
}

// async 16B/lane global -> LDS (wave-uniform LDS base + lane*16)
__device__ __forceinline__ void async16(const void* g, void* l) {
    __builtin_amdgcn_global_load_lds(
        (const __attribute__((address_space(1))) unsigned int*)g,
        (__attribute__((address_space(3))) unsigned int*)l,
        16, 0, 0);
}

// ---------------------------------------------------------------------------
// quant_x v3: x[M,K] f32 -> Xd[M,K] bf16 (dequantized). 8 lanes per 128-elem
// fp8 block, 16 elems/lane (4 x float4, interleaved so each 8-lane group's
// loads are 128 B contiguous). amax: 15 in-lane fmax + 3 shfl_xor rounds.
// ---------------------------------------------------------------------------
__global__ __launch_bounds__(256) void quant_x_kernel(
        const float* __restrict__ x, ushort_t* __restrict__ xd) {
    size_t gt = (size_t)blockIdx.x * 256 + threadIdx.x;
    int l8 = threadIdx.x & 7;
    size_t base = (gt >> 3) * 128 + (size_t)l8 * 4;   // block*128 + lane slot
    float4 v0 = *(const float4*)(x + base);
    float4 v1 = *(const float4*)(x + base + 32);
    float4 v2 = *(const float4*)(x + base + 64);
    float4 v3 = *(const float4*)(x + base + 96);
    float a01 = fmaxf(fmaxf(fmaxf(fabsf(v0.x), fabsf(v0.y)),
                            fmaxf(fabsf(v0.z), fabsf(v0.w))),
                      fmaxf(fmaxf(fabsf(v1.x), fabsf(v1.y)),
                            fmaxf(fabsf(v1.z), fabsf(v1.w))));
    float a23 = fmaxf(fmaxf(fmaxf(fabsf(v2.x), fabsf(v2.y)),
                            fmaxf(fabsf(v2.z), fabsf(v2.w))),
                      fmaxf(fmaxf(fabsf(v3.x), fabsf(v3.y)),
                            fmaxf(fabsf(v3.z), fabsf(v3.w))));
    float amax = fmaxf(a01, a23);
    amax = fmaxf(amax, __shfl_xor(amax, 1, 64));
    amax = fmaxf(amax, __shfl_xor(amax, 2, 64));
    amax = fmaxf(amax, __shfl_xor(amax, 4, 64));
    float scale = fmaxf(amax / 448.0f, 1e-12f);
    ushort4 o;
    o.x = f32_to_bf16(fp8_round_trip(v0.x / scale) * scale);
    o.y = f32_to_bf16(fp8_round_trip(v0.y / scale) * scale);
    o.z = f32_to_bf16(fp8_round_trip(v0.z / scale) * scale);
    o.w = f32_to_bf16(fp8_round_trip(v0.w / scale) * scale);
    *(ushort4*)(xd + base) = o;
    o.x = f32_to_bf16(fp8_round_trip(v1.x / scale) * scale);
    o.y = f32_to_bf16(fp8_round_trip(v1.y / scale) * scale);
    o.z = f32_to_bf16(fp8_round_trip(v1.z / scale) * scale);
    o.w = f32_to_bf16(fp8_round_trip(v1.w / scale) * scale);
    *(ushort4*)(xd + base + 32) = o;
    o.x = f32_to_bf16(fp8_round_trip(v2.x / scale) * scale);
    o.y = f32_to_bf16(fp8_round_trip(v2.y / scale) * scale);
    o.z = f32_to_bf16(fp8_round_trip(v2.z / scale) * scale);
    o.w = f32_to_bf16(fp8_round_trip(v2.w / scale) * scale);
    *(ushort4*)(xd + base + 64) = o;
    o.x = f32_to_bf16(fp8_round_trip(v3.x / scale) * scale);
    o.y = f32_to_bf16(fp8_round_trip(v3.y / scale) * scale);
    o.z = f32_to_bf16(fp8_round_trip(v3.z / scale) * scale);
    o.w = f32_to_bf16(fp8_round_trip(v3.w / scale) * scale);
    *(ushort4*)(xd + base + 96) = o;
}

// ---------------------------------------------------------------------------
// quant_w v3: w[K,N] f32 -> Bt[N,K] bf16 (dequantized + transposed).
// 64 k-rows x 128 n-cols per block; 8 lanes per row-block, 16 elems/lane,
// 2 iters of 32 rows. LDS transpose (stride 65) + coalesced write unchanged.
// ---------------------------------------------------------------------------
__global__ __launch_bounds__(256) void quant_w_kernel(
        const float* __restrict__ w, ushort_t* __restrict__ bt,
        int K, int N) {
    __shared__ float lds[128 * 65];
    int k0 = blockIdx.x * 64;
    int n0 = blockIdx.y * 128;
    int t = threadIdx.x;
    int l8 = t & 7;
    int rloc = t >> 3;                 // 0..31

    #pragma unroll
    for (int it = 0; it < 2; ++it) {
        int klocal = it * 32 + rloc;
        const float* src = w + (size_t)(k0 + klocal) * N + n0 + l8 * 4;
        float4 v0 = *(const float4*)(src);
        float4 v1 = *(const float4*)(src + 32);
        float4 v2 = *(const float4*)(src + 64);
        float4 v3 = *(const float4*)(src + 96);
        float a01 = fmaxf(fmaxf(fmaxf(fabsf(v0.x), fabsf(v0.y)),
                                fmaxf(fabsf(v0.z), fabsf(v0.w))),
                          fmaxf(fmaxf(fabsf(v1.x), fabsf(v1.y)),
                                fmaxf(fabsf(v1.z), fabsf(v1.w))));
        float a23 = fmaxf(fmaxf(fmaxf(fabsf(v2.x), fabsf(v2.y)),
                                fmaxf(fabsf(v2.z), fabsf(v2.w))),
                          fmaxf(fmaxf(fabsf(v3.x), fabsf(v3.y)),
                                fmaxf(fabsf(v3.z), fabsf(v3.w))));
        float amax = fmaxf(a01, a23);
        amax = fmaxf(amax, __shfl_xor(amax, 1, 64));
        amax = fmaxf(amax, __shfl_xor(amax, 2, 64));
        amax = fmaxf(amax, __shfl_xor(amax, 4, 64));
        float scale = fmaxf(amax / 448.0f, 1e-12f);
        int nl = l8 * 4;
        lds[(nl +  0) * 65 + klocal] = fp8_round_trip(v0.x / scale) * scale;
        lds[(nl +  1) * 65 + klocal] = fp8_round_trip(v0.y / scale) * scale;
        lds[(nl +  2) * 65 + klocal] = fp8_round_trip(v0.z / scale) * scale;
        lds[(nl +  3) * 65 + klocal] = fp8_round_trip(v0.w / scale) * scale;
        lds[(nl + 32) * 65 + klocal] = fp8_round_trip(v1.x / scale) * scale;
        lds[(nl + 33) * 65 + klocal] = fp8_round_trip(v1.y / scale) * scale;
        lds[(nl + 34) * 65 + klocal] = fp8_round_trip(v1.z / scale) * scale;
        lds[(nl + 35) * 65 + klocal] = fp8_round_trip(v1.w / scale) * scale;
        lds[(nl + 64) * 65 + klocal] = fp8_round_trip(v2.x / scale) * scale;
        lds[(nl + 65) * 65 + klocal] = fp8_round_trip(v2.y / scale) * scale;
        lds[(nl + 66) * 65 + klocal] = fp8_round_trip(v2.z / scale) * scale;
        lds[(nl + 67) * 65 + klocal] = fp8_round_trip(v2.w / scale) * scale;
        lds[(nl + 96) * 65 + klocal] = fp8_round_trip(v3.x / scale) * scale;
        lds[(nl + 97) * 65 + klocal] = fp8_round_trip(v3.y / scale) * scale;
        lds[(nl + 98) * 65 + klocal] = fp8_round_trip(v3.z / scale) * scale;
        lds[(nl + 99) * 65 + klocal] = fp8_round_trip(v3.w / scale) * scale;
    }
    __syncthreads();
    #pragma unroll
    for (int it = 0; it < 8; ++it) {
        int idx = it * 256 + t;
        int j = idx >> 4;
        int c = idx & 15;
        const float* p = &lds[j * 65 + c * 4];
        ushort4 o;
        o.x = f32_to_bf16(p[0]);
        o.y = f32_to_bf16(p[1]);
        o.z = f32_to_bf16(p[2]);
        o.w = f32_to_bf16(p[3]);
        *(ushort4*)(bt + (size_t)(n0 + j) * K + k0 + c * 4) = o;
    }
}

// ---------------------------------------------------------------------------
// gemm256: C[M,N] = A[M,K](bf16) * Bt[N,K](bf16)^T + bias.
// 256x256 tile, BK=32, 512 threads = 8 waves (wr in {0,1} x wcn in {0..3});
// per-wave output 128x64 = acc[8][4]. LDS: 3 buffers x (A 16K | B 16K).
//
// Per step (1 K-tile): WAITV(4) confirms tile t (issued step t-2);
// s_barrier (also retires WAR on buf (t+2)%3 = (t-1)%3); 12 pinned
// ds_read_b128 [b0,b1,a0..a7,b2,b3]; 4 staggered stages of tile t+2;
// WAITL(6)->Q0(m0-3 x n0-1), WAITL(2)->Q1(m4-7 x n0-1), WAITL(0)->Q2,Q3.
// vmcnt ledger (4 gload_lds/wave/tile): at step top outstanding = 8
// (tiles t, t+1); WAITV(4) -> tile t done; +4 during step -> 8 at next top.
// Swizzle: row r, 16B-slot s stored at slot s^(r&3); reads use
// slot = quad^(l16&3); staging pre-swizzles the per-lane global column
// (linear gload_lds dest). Bijective per 1024-B row-block -> conflict-free.
// ---------------------------------------------------------------------------

#define GBAR()    asm volatile("s_barrier" ::: "memory")
#define WAITL(n)  asm volatile("s_waitcnt lgkmcnt(" #n ")" ::: "memory")
#define WAITV(n)  asm volatile("s_waitcnt vmcnt(" #n ")" ::: "memory")
#define SCHED0    __builtin_amdgcn_sched_barrier(0)
#define SETP(n)   __builtin_amdgcn_s_setprio(n)
#define MFMA16    __builtin_amdgcn_mfma_f32_16x16x32_bf16

#define DSR(dst, base, off) \
    asm volatile("ds_read_b128 %0, %1 offset:" #off : "=v"(dst) : "v"(base))

// staging: one async16 per wave per quarter-tile (A/B half x 128 rows)
#define STAGE_A0(base, kt) async16(aSrc + (size_t)(kt) * 32, \
        (char*)sm + (base) + wid * 1024)
#define STAGE_A1(base, kt) async16(aSrc + (size_t)128 * K + (size_t)(kt) * 32, \
        (char*)sm + (base) + 8192 + wid * 1024)
#define STAGE_B0(base, kt) async16(bSrc + (size_t)(kt) * 32, \
        (char*)sm + (base) + 16384 + wid * 1024)
#define STAGE_B1(base, kt) async16(bSrc + (size_t)128 * K + (size_t)(kt) * 32, \
        (char*)sm + (base) + 24576 + wid * 1024)

#define QUAD(mb, nb) do {                                                    \
    _Pragma("unroll") for (int m_ = 0; m_ < 4; ++m_)                         \
    _Pragma("unroll") for (int n_ = 0; n_ < 2; ++n_)                         \
        acc[(mb) + m_][(nb) + n_] = MFMA16(a[(mb) + m_], b[(nb) + n_],       \
                                           acc[(mb) + m_][(nb) + n_], 0, 0, 0); \
} while (0)

__global__ __launch_bounds__(512, 2) void gemm256_kernel(
        const ushort_t* __restrict__ A, const ushort_t* __restrict__ B,
        const float* __restrict__ bias, float* __restrict__ C,
        int M, int N, int K) {
    __shared__ ushort_t sm[3 * 16384];   // 96 KiB: 3 x (A 16K | B 16K)

    const int t = threadIdx.x;
    const int wid = t >> 6;
    const int lane = t & 63;
    const int quad = lane >> 4, l16 = lane & 15;
    const int wr = wid >> 2, wcn = wid & 3;

    // T1: XCD-aware swizzle on flattened block id (nwg = 1024, % 8 == 0)
    const int nwg = gridDim.x;
    const int bid = blockIdx.x;
    int wg = bid;
    if ((nwg & 7) == 0) { const int cpx = nwg >> 3; wg = (bid & 7) * cpx + (bid >> 3); }
    const int nbn = N >> 8;
    const int bm = wg / nbn, bn = wg % nbn;

    // staging map: thread t covers LDS linear byte t*16 per quarter-tile:
    // row = t>>2 (0..127), 16B-slot = t&3; pre-swizzled global slot ^= row&3.
    const int srow = t >> 2;
    const int gcol = (((t & 3) ^ (srow & 3)) << 3);   // elems
    const ushort_t* aSrc = A + (size_t)(bm * 256 + srow) * K + gcol;
    const ushort_t* bSrc = B + (size_t)(bn * 256 + srow) * K + gcol;

    // read map: row byte-base + swizzled 16B slot (slot = quad ^ (row&3))
    const int swz = (quad ^ (l16 & 3)) << 4;
    const int aOff = wr * 8192 + l16 * 64 + swz;            // within A region
    const int bOff = 16384 + wcn * 4096 + l16 * 64 + swz;   // within B region
    as3ch* lds3 = (as3ch*)sm;

    f32x4 acc[8][4] = {};
    short8 a[8], b[4];

    const int NT = K >> 5;     // 128 K-steps
    unsigned prv = 65536, cur = 0, nxt = 32768;

    // prologue: stage tile0 -> buf0, tile1 -> buf1 (4 loads each per wave)
    STAGE_A0(0, 0); STAGE_A1(0, 0); STAGE_B0(0, 0); STAGE_B1(0, 0);
    STAGE_A0(32768, 1); STAGE_A1(32768, 1); STAGE_B0(32768, 1); STAGE_B1(32768, 1);

    for (int ts = 0; ts < NT; ++ts) {
        const int kt = (ts + 2 < NT) ? ts + 2 : 0;   // clamped, never computed
        WAITV(4);        // tile ts confirmed (issued 2 steps ago)
        GBAR();          // cross-wave: ts visible; buf (ts+2)%3 WAR-free
        SCHED0;
        as3ch* aC = lds3 + cur + aOff;
        as3ch* bC = lds3 + cur + bOff;
        DSR(b[0], bC, 0);    DSR(b[1], bC, 1024);
        DSR(a[0], aC, 0);    DSR(a[1], aC, 1024);
        DSR(a[2], aC, 2048); DSR(a[3], aC, 3072);
        DSR(a[4], aC, 4096); DSR(a[5], aC, 5120);
        DSR(a[6], aC, 6144); DSR(a[7], aC, 7168);
        DSR(b[2], bC, 2048); DSR(b[3], bC, 3072);
        STAGE_A0(prv, kt);
        WAITL(6); SCHED0; SETP(1);
        QUAD(0, 0);
        SETP(0);
        STAGE_A1(prv, kt);
        WAITL(2); SCHED0; SETP(1);
        QUAD(4, 0);
        SETP(0);
        STAGE_B0(prv, kt);
        WAITL(0); SCHED0; SETP(1);
        QUAD(0, 2);
        SETP(0);
        STAGE_B1(prv, kt);
        SETP(1);
        QUAD(4, 2);
        SETP(0);
        unsigned tmp = prv; prv = cur; cur = nxt; nxt = tmp;
    }

    // epilogue: C/D layout col = lane&15, row = quad*4 + reg (m89/m91)
    #pragma unroll
    for (int nt = 0; nt < 4; ++nt) {
        const int col = bn * 256 + wcn * 64 + nt * 16 + l16;
        const float bv = bias[col];
        #pragma unroll
        for (int mt = 0; mt < 8; ++mt) {
            const int row0 = bm * 256 + wr * 128 + mt * 16 + quad * 4;
            #pragma unroll
            for (int r = 0; r < 4; ++r)
                C[(size_t)(row0 + r) * N + col] = acc[mt][nt][r] + bv;
        }
    }
}

// ---------------------------------------------------------------------------
extern "C" void kernel_launch(void* const* d_in, const int* in_sizes, int n_in,
                              void* d_out, int out_size, void* d_ws, size_t ws_size,
                              hipStream_t stream) {
    const float* x    = (const float*)d_in[0];
    const float* w    = (const float*)d_in[1];
    const float* bias = (const float*)d_in[2];
    float* out = (float*)d_out;

    const int N = in_sizes[2];              // 4096
    const int K = in_sizes[1] / N;          // 4096
    const int M = in_sizes[0] / K;          // 16384

    ushort_t* xd = (ushort_t*)d_ws;                  // M*K bf16
    ushort_t* bt = xd + (size_t)M * K;               // N*K bf16
    // requires ws_size >= (M*K + N*K)*2 = 160 MB

    quant_x_kernel<<<(size_t)M * K / 4096, 256, 0, stream>>>(x, xd);
    quant_w_kernel<<<dim3(K / 64, N / 128), 256, 0, stream>>>(w, bt, K, N);
    gemm256_kernel<<<dim3((M / 256) * (N / 256)), 512, 0, stream>>>(
        xd, bt, bias, out, M, N, K);
}

// Round 7
// 949.433 us; speedup vs baseline: 1.0249x; 1.0249x over previous
//
#include <hip/hip_runtime.h>

// ---------------------------------------------------------------------------
// TPUGEMMLinear: blockwise-fp8 quantize (block=128) of x[M,K] (along K) and
// w[K,N] (along N), dequant-scaled fp32 GEMM + bias.
// R7 == R6 with the BK=32 swizzle key FIXED (2 expressions). R6 measured
// bank-conflict 5.03e7: slot key (row&3) collapses on even rows (64-B rows
// give only one row bank-bit). Fixed key (row>>1)&3 -> bank start =
// 16*(l16&1) + 4*(quad ^ ((l16>>1)&3)): every consecutive 8-lane block hits
// all 8 16B-bank-groups (the R3-vs-R6 pair shows this is the HW's service
// rule). Structure unchanged: BK=32, triple buffer (96 KiB), 1 s_barrier +
// 1 WAITV(4) per K-step, 12 pinned ds_read_b128 + 4 staggered stages,
// WAITL(6)/(2)/(0) ladder, setprio around MFMA quadrants.
// Quant kernels v3 unchanged.
// Workspace: Xd bf16 [M*K] | Bt bf16 [N*K]  (160 MB).
// ---------------------------------------------------------------------------

typedef __attribute__((ext_vector_type(8))) short short8;   // 8 x bf16 frag
typedef __attribute__((ext_vector_type(4))) float f32x4;
typedef unsigned short ushort_t;
typedef __attribute__((address_space(3))) const char as3ch;

__device__ __forceinline__ float fp8_round_trip(float v) {
    int p = __builtin_amdgcn_cvt_pk_fp8_f32(v, v, 0, false);
    return __builtin_amdgcn_cvt_f32_fp8(p, 0);
}

__device__ __forceinline__ ushort_t f32_to_bf16(float f) {
    union { float f; unsigned u; } un; un.f = f;
    unsigned r = un.u + 0x7fffu + ((un.u >> 16) & 1u);
    return (ushort_t)(r >> 16);
}

// async 16B/lane global -> LDS (wave-uniform LDS base + lane*16)
__device__ __forceinline__ void async16(const void* g, void* l) {
    __builtin_amdgcn_global_load_lds(
        (const __attribute__((address_space(1))) unsigned int*)g,
        (__attribute__((address_space(3))) unsigned int*)l,
        16, 0, 0);
}

// ---------------------------------------------------------------------------
// quant_x v3: x[M,K] f32 -> Xd[M,K] bf16 (dequantized). 8 lanes per 128-elem
// fp8 block, 16 elems/lane (4 x float4, interleaved so each 8-lane group's
// loads are 128 B contiguous). amax: 15 in-lane fmax + 3 shfl_xor rounds.
// ---------------------------------------------------------------------------
__global__ __launch_bounds__(256) void quant_x_kernel(
        const float* __restrict__ x, ushort_t* __restrict__ xd) {
    size_t gt = (size_t)blockIdx.x * 256 + threadIdx.x;
    int l8 = threadIdx.x & 7;
    size_t base = (gt >> 3) * 128 + (size_t)l8 * 4;   // block*128 + lane slot
    float4 v0 = *(const float4*)(x + base);
    float4 v1 = *(const float4*)(x + base + 32);
    float4 v2 = *(const float4*)(x + base + 64);
    float4 v3 = *(const float4*)(x + base + 96);
    float a01 = fmaxf(fmaxf(fmaxf(fabsf(v0.x), fabsf(v0.y)),
                            fmaxf(fabsf(v0.z), fabsf(v0.w))),
                      fmaxf(fmaxf(fabsf(v1.x), fabsf(v1.y)),
                            fmaxf(fabsf(v1.z), fabsf(v1.w))));
    float a23 = fmaxf(fmaxf(fmaxf(fabsf(v2.x), fabsf(v2.y)),
                            fmaxf(fabsf(v2.z), fabsf(v2.w))),
                      fmaxf(fmaxf(fabsf(v3.x), fabsf(v3.y)),
                            fmaxf(fabsf(v3.z), fabsf(v3.w))));
    float amax = fmaxf(a01, a23);
    amax = fmaxf(amax, __shfl_xor(amax, 1, 64));
    amax = fmaxf(amax, __shfl_xor(amax, 2, 64));
    amax = fmaxf(amax, __shfl_xor(amax, 4, 64));
    float scale = fmaxf(amax / 448.0f, 1e-12f);
    ushort4 o;
    o.x = f32_to_bf16(fp8_round_trip(v0.x / scale) * scale);
    o.y = f32_to_bf16(fp8_round_trip(v0.y / scale) * scale);
    o.z = f32_to_bf16(fp8_round_trip(v0.z / scale) * scale);
    o.w = f32_to_bf16(fp8_round_trip(v0.w / scale) * scale);
    *(ushort4*)(xd + base) = o;
    o.x = f32_to_bf16(fp8_round_trip(v1.x / scale) * scale);
    o.y = f32_to_bf16(fp8_round_trip(v1.y / scale) * scale);
    o.z = f32_to_bf16(fp8_round_trip(v1.z / scale) * scale);
    o.w = f32_to_bf16(fp8_round_trip(v1.w / scale) * scale);
    *(ushort4*)(xd + base + 32) = o;
    o.x = f32_to_bf16(fp8_round_trip(v2.x / scale) * scale);
    o.y = f32_to_bf16(fp8_round_trip(v2.y / scale) * scale);
    o.z = f32_to_bf16(fp8_round_trip(v2.z / scale) * scale);
    o.w = f32_to_bf16(fp8_round_trip(v2.w / scale) * scale);
    *(ushort4*)(xd + base + 64) = o;
    o.x = f32_to_bf16(fp8_round_trip(v3.x / scale) * scale);
    o.y = f32_to_bf16(fp8_round_trip(v3.y / scale) * scale);
    o.z = f32_to_bf16(fp8_round_trip(v3.z / scale) * scale);
    o.w = f32_to_bf16(fp8_round_trip(v3.w / scale) * scale);
    *(ushort4*)(xd + base + 96) = o;
}

// ---------------------------------------------------------------------------
// quant_w v3: w[K,N] f32 -> Bt[N,K] bf16 (dequantized + transposed).
// ---------------------------------------------------------------------------
__global__ __launch_bounds__(256) void quant_w_kernel(
        const float* __restrict__ w, ushort_t* __restrict__ bt,
        int K, int N) {
    __shared__ float lds[128 * 65];
    int k0 = blockIdx.x * 64;
    int n0 = blockIdx.y * 128;
    int t = threadIdx.x;
    int l8 = t & 7;
    int rloc = t >> 3;                 // 0..31

    #pragma unroll
    for (int it = 0; it < 2; ++it) {
        int klocal = it * 32 + rloc;
        const float* src = w + (size_t)(k0 + klocal) * N + n0 + l8 * 4;
        float4 v0 = *(const float4*)(src);
        float4 v1 = *(const float4*)(src + 32);
        float4 v2 = *(const float4*)(src + 64);
        float4 v3 = *(const float4*)(src + 96);
        float a01 = fmaxf(fmaxf(fmaxf(fabsf(v0.x), fabsf(v0.y)),
                                fmaxf(fabsf(v0.z), fabsf(v0.w))),
                          fmaxf(fmaxf(fabsf(v1.x), fabsf(v1.y)),
                                fmaxf(fabsf(v1.z), fabsf(v1.w))));
        float a23 = fmaxf(fmaxf(fmaxf(fabsf(v2.x), fabsf(v2.y)),
                                fmaxf(fabsf(v2.z), fabsf(v2.w))),
                          fmaxf(fmaxf(fabsf(v3.x), fabsf(v3.y)),
                                fmaxf(fabsf(v3.z), fabsf(v3.w))));
        float amax = fmaxf(a01, a23);
        amax = fmaxf(amax, __shfl_xor(amax, 1, 64));
        amax = fmaxf(amax, __shfl_xor(amax, 2, 64));
        amax = fmaxf(amax, __shfl_xor(amax, 4, 64));
        float scale = fmaxf(amax / 448.0f, 1e-12f);
        int nl = l8 * 4;
        lds[(nl +  0) * 65 + klocal] = fp8_round_trip(v0.x / scale) * scale;
        lds[(nl +  1) * 65 + klocal] = fp8_round_trip(v0.y / scale) * scale;
        lds[(nl +  2) * 65 + klocal] = fp8_round_trip(v0.z / scale) * scale;
        lds[(nl +  3) * 65 + klocal] = fp8_round_trip(v0.w / scale) * scale;
        lds[(nl + 32) * 65 + klocal] = fp8_round_trip(v1.x / scale) * scale;
        lds[(nl + 33) * 65 + klocal] = fp8_round_trip(v1.y / scale) * scale;
        lds[(nl + 34) * 65 + klocal] = fp8_round_trip(v1.z / scale) * scale;
        lds[(nl + 35) * 65 + klocal] = fp8_round_trip(v1.w / scale) * scale;
        lds[(nl + 64) * 65 + klocal] = fp8_round_trip(v2.x / scale) * scale;
        lds[(nl + 65) * 65 + klocal] = fp8_round_trip(v2.y / scale) * scale;
        lds[(nl + 66) * 65 + klocal] = fp8_round_trip(v2.z / scale) * scale;
        lds[(nl + 67) * 65 + klocal] = fp8_round_trip(v2.w / scale) * scale;
        lds[(nl + 96) * 65 + klocal] = fp8_round_trip(v3.x / scale) * scale;
        lds[(nl + 97) * 65 + klocal] = fp8_round_trip(v3.y / scale) * scale;
        lds[(nl + 98) * 65 + klocal] = fp8_round_trip(v3.z / scale) * scale;
        lds[(nl + 99) * 65 + klocal] = fp8_round_trip(v3.w / scale) * scale;
    }
    __syncthreads();
    #pragma unroll
    for (int it = 0; it < 8; ++it) {
        int idx = it * 256 + t;
        int j = idx >> 4;
        int c = idx & 15;
        const float* p = &lds[j * 65 + c * 4];
        ushort4 o;
        o.x = f32_to_bf16(p[0]);
        o.y = f32_to_bf16(p[1]);
        o.z = f32_to_bf16(p[2]);
        o.w = f32_to_bf16(p[3]);
        *(ushort4*)(bt + (size_t)(n0 + j) * K + k0 + c * 4) = o;
    }
}

// ---------------------------------------------------------------------------
// gemm256: C[M,N] = A[M,K](bf16) * Bt[N,K](bf16)^T + bias.
// 256x256 tile, BK=32, 512 threads = 8 waves (wr in {0,1} x wcn in {0..3});
// per-wave output 128x64 = acc[8][4]. LDS: 3 buffers x (A 16K | B 16K).
//
// Per step (1 K-tile): WAITV(4) confirms tile t (issued step t-2);
// s_barrier (also retires WAR on buf (t+2)%3 = (t-1)%3); 12 pinned
// ds_read_b128 [b0,b1,a0..a7,b2,b3]; 4 staggered stages of tile t+2;
// WAITL(6)->Q0, WAITL(2)->Q1, WAITL(0)->Q2,Q3.
// vmcnt ledger (4 gload_lds/wave/tile): top-of-step outstanding = 8
// (tiles t, t+1); WAITV(4) -> tile t done; +4 during step -> 8 at next top.
//
// Swizzle (R7 FIX): row r, 16B-slot s stored at slot s ^ ((r>>1)&3); reads
// at slot quad ^ ((l16>>1)&3) -> bank start = 16*(l16&1) +
// 4*(quad^((l16>>1)&3)): each consecutive 8-lane block covers all 8
// bank-groups (service-cycle conflict-free; R3-vs-R6 evidence). Invariant
// under +16-row offsets, so per-lane constant addr + offset: immediates OK.
// Staging pre-swizzles the per-lane global column with the same involution
// (linear global_load_lds dest): s_global = (t&3) ^ ((t>>3)&3).
// ---------------------------------------------------------------------------

#define GBAR()    asm volatile("s_barrier" ::: "memory")
#define WAITL(n)  asm volatile("s_waitcnt lgkmcnt(" #n ")" ::: "memory")
#define WAITV(n)  asm volatile("s_waitcnt vmcnt(" #n ")" ::: "memory")
#define SCHED0    __builtin_amdgcn_sched_barrier(0)
#define SETP(n)   __builtin_amdgcn_s_setprio(n)
#define MFMA16    __builtin_amdgcn_mfma_f32_16x16x32_bf16

#define DSR(dst, base, off) \
    asm volatile("ds_read_b128 %0, %1 offset:" #off : "=v"(dst) : "v"(base))

// staging: one async16 per wave per quarter-tile (A/B half x 128 rows)
#define STAGE_A0(base, kt) async16(aSrc + (size_t)(kt) * 32, \
        (char*)sm + (base) + wid * 1024)
#define STAGE_A1(base, kt) async16(aSrc + (size_t)128 * K + (size_t)(kt) * 32, \
        (char*)sm + (base) + 8192 + wid * 1024)
#define STAGE_B0(base, kt) async16(bSrc + (size_t)(kt) * 32, \
        (char*)sm + (base) + 16384 + wid * 1024)
#define STAGE_B1(base, kt) async16(bSrc + (size_t)128 * K + (size_t)(kt) * 32, \
        (char*)sm + (base) + 24576 + wid * 1024)

#define QUAD(mb, nb) do {                                                    \
    _Pragma("unroll") for (int m_ = 0; m_ < 4; ++m_)                         \
    _Pragma("unroll") for (int n_ = 0; n_ < 2; ++n_)                         \
        acc[(mb) + m_][(nb) + n_] = MFMA16(a[(mb) + m_], b[(nb) + n_],       \
                                           acc[(mb) + m_][(nb) + n_], 0, 0, 0); \
} while (0)

__global__ __launch_bounds__(512, 2) void gemm256_kernel(
        const ushort_t* __restrict__ A, const ushort_t* __restrict__ B,
        const float* __restrict__ bias, float* __restrict__ C,
        int M, int N, int K) {
    __shared__ ushort_t sm[3 * 16384];   // 96 KiB: 3 x (A 16K | B 16K)

    const int t = threadIdx.x;
    const int wid = t >> 6;
    const int lane = t & 63;
    const int quad = lane >> 4, l16 = lane & 15;
    const int wr = wid >> 2, wcn = wid & 3;

    // T1: XCD-aware swizzle on flattened block id (nwg = 1024, % 8 == 0)
    const int nwg = gridDim.x;
    const int bid = blockIdx.x;
    int wg = bid;
    if ((nwg & 7) == 0) { const int cpx = nwg >> 3; wg = (bid & 7) * cpx + (bid >> 3); }
    const int nbn = N >> 8;
    const int bm = wg / nbn, bn = wg % nbn;

    // staging map: thread t covers LDS linear byte t*16 per quarter-tile:
    // row = t>>2 (0..127), 16B-slot = t&3; pre-swizzled global slot
    // = (t&3) ^ ((row>>1)&3) = (t&3) ^ ((t>>3)&3).   [R7 fix]
    const int srow = t >> 2;
    const int gcol = (((t & 3) ^ ((t >> 3) & 3)) << 3);   // elems
    const ushort_t* aSrc = A + (size_t)(bm * 256 + srow) * K + gcol;
    const ushort_t* bSrc = B + (size_t)(bn * 256 + srow) * K + gcol;

    // read map: row byte-base + swizzled 16B slot = quad ^ ((l16>>1)&3) [R7]
    const int swz = (quad ^ ((l16 >> 1) & 3)) << 4;
    const int aOff = wr * 8192 + l16 * 64 + swz;            // within A region
    const int bOff = 16384 + wcn * 4096 + l16 * 64 + swz;   // within B region
    as3ch* lds3 = (as3ch*)sm;

    f32x4 acc[8][4] = {};
    short8 a[8], b[4];

    const int NT = K >> 5;     // 128 K-steps
    unsigned prv = 65536, cur = 0, nxt = 32768;

    // prologue: stage tile0 -> buf0, tile1 -> buf1 (4 loads each per wave)
    STAGE_A0(0, 0); STAGE_A1(0, 0); STAGE_B0(0, 0); STAGE_B1(0, 0);
    STAGE_A0(32768, 1); STAGE_A1(32768, 1); STAGE_B0(32768, 1); STAGE_B1(32768, 1);

    for (int ts = 0; ts < NT; ++ts) {
        const int kt = (ts + 2 < NT) ? ts + 2 : 0;   // clamped, never computed
        WAITV(4);        // tile ts confirmed (issued 2 steps ago)
        GBAR();          // cross-wave: ts visible; buf (ts+2)%3 WAR-free
        SCHED0;
        as3ch* aC = lds3 + cur + aOff;
        as3ch* bC = lds3 + cur + bOff;
        DSR(b[0], bC, 0);    DSR(b[1], bC, 1024);
        DSR(a[0], aC, 0);    DSR(a[1], aC, 1024);
        DSR(a[2], aC, 2048); DSR(a[3], aC, 3072);
        DSR(a[4], aC, 4096); DSR(a[5], aC, 5120);
        DSR(a[6], aC, 6144); DSR(a[7], aC, 7168);
        DSR(b[2], bC, 2048); DSR(b[3], bC, 3072);
        STAGE_A0(prv, kt);
        WAITL(6); SCHED0; SETP(1);
        QUAD(0, 0);
        SETP(0);
        STAGE_A1(prv, kt);
        WAITL(2); SCHED0; SETP(1);
        QUAD(4, 0);
        SETP(0);
        STAGE_B0(prv, kt);
        WAITL(0); SCHED0; SETP(1);
        QUAD(0, 2);
        SETP(0);
        STAGE_B1(prv, kt);
        SETP(1);
        QUAD(4, 2);
        SETP(0);
        unsigned tmp = prv; prv = cur; cur = nxt; nxt = tmp;
    }

    // epilogue: C/D layout col = lane&15, row = quad*4 + reg (m89/m91)
    #pragma unroll
    for (int nt = 0; nt < 4; ++nt) {
        const int col = bn * 256 + wcn * 64 + nt * 16 + l16;
        const float bv = bias[col];
        #pragma unroll
        for (int mt = 0; mt < 8; ++mt) {
            const int row0 = bm * 256 + wr * 128 + mt * 16 + quad * 4;
            #pragma unroll
            for (int r = 0; r < 4; ++r)
                C[(size_t)(row0 + r) * N + col] = acc[mt][nt][r] + bv;
        }
    }
}

// ---------------------------------------------------------------------------
extern "C" void kernel_launch(void* const* d_in, const int* in_sizes, int n_in,
                              void* d_out, int out_size, void* d_ws, size_t ws_size,
                              hipStream_t stream) {
    const float* x    = (const float*)d_in[0];
    const float* w    = (const float*)d_in[1];
    const float* bias = (const float*)d_in[2];
    float* out = (float*)d_out;

    const int N = in_sizes[2];              // 4096
    const int K = in_sizes[1] / N;          // 4096
    const int M = in_sizes[0] / K;          // 16384

    ushort_t* xd = (ushort_t*)d_ws;                  // M*K bf16
    ushort_t* bt = xd + (size_t)M * K;               // N*K bf16
    // requires ws_size >= (M*K + N*K)*2 = 160 MB

    quant_x_kernel<<<(size_t)M * K / 4096, 256, 0, stream>>>(x, xd);
    quant_w_kernel<<<dim3(K / 64, N / 128), 256, 0, stream>>>(w, bt, K, N);
    gemm256_kernel<<<dim3((M / 256) * (N / 256)), 512, 0, stream>>>(
        xd, bt, bias, out, M, N, K);
}